// Round 1
// baseline (1019.017 us; speedup 1.0000x reference)
//
#include <hip/hip_runtime.h>
#include <math.h>

#define D 256
#define NSEG 8192
#define SPB 16   // segments per block in the small projection GEMM

__device__ __forceinline__ int lower_bound_dev(const int* __restrict__ a, int n, int key) {
    int lo = 0, hi = n;
    while (lo < hi) {
        int mid = (lo + hi) >> 1;
        if (a[mid] < key) lo = mid + 1; else hi = mid;
    }
    return lo;
}

// K1: per-segment sum of embedding rows + counts.
// One block (256 threads = 4 waves) per segment; wave w handles rows start+w, start+w+4, ...
// Lane l holds dims [4l, 4l+4) as float4.
__global__ void seg_sum_kernel(const float* __restrict__ emb,
                               const int* __restrict__ obj, int T,
                               float* __restrict__ S, int* __restrict__ counts) {
    const int seg   = blockIdx.x;
    const int start = lower_bound_dev(obj, T, seg);
    const int end   = lower_bound_dev(obj, T, seg + 1);
    const int tid  = threadIdx.x;
    const int lane = tid & 63;
    const int w    = tid >> 6;

    float4 acc = make_float4(0.f, 0.f, 0.f, 0.f);
    for (int r = start + w; r < end; r += 4) {
        const float4 e = *reinterpret_cast<const float4*>(emb + (size_t)r * D + lane * 4);
        acc.x += e.x; acc.y += e.y; acc.z += e.z; acc.w += e.w;
    }

    __shared__ float sm[4][D];
    *reinterpret_cast<float4*>(&sm[w][lane * 4]) = acc;
    __syncthreads();

    float v = sm[0][tid] + sm[1][tid] + sm[2][tid] + sm[3][tid];
    S[(size_t)seg * D + tid] = v;
    if (tid == 0) counts[seg] = end - start;
}

// K2: tg[n][j] = tanh( (S[n,:] @ W[:,j]) / max(cnt,1) )
// 16 segments per block so each W element is read once per 16 segments (W stays L2-hot).
__global__ void proj_tanh_kernel(const float* __restrict__ S,
                                 const int* __restrict__ counts,
                                 const float* __restrict__ W,
                                 float* __restrict__ tg) {
    const int n0 = blockIdx.x * SPB;
    const int j  = threadIdx.x;

    __shared__ float Sl[SPB][D];
    __shared__ float inv[SPB];
    #pragma unroll
    for (int s = 0; s < SPB; ++s) Sl[s][j] = S[(size_t)(n0 + s) * D + j];
    if (j < SPB) {
        int c = counts[n0 + j];
        inv[j] = 1.0f / (float)(c > 1 ? c : 1);
    }
    __syncthreads();

    float acc[SPB];
    #pragma unroll
    for (int s = 0; s < SPB; ++s) acc[s] = 0.f;

    for (int k = 0; k < D; ++k) {
        const float wkj = W[k * D + j];
        #pragma unroll
        for (int s = 0; s < SPB; ++s) acc[s] += Sl[s][k] * wkj;  // Sl[s][k] is a broadcast read
    }

    #pragma unroll
    for (int s = 0; s < SPB; ++s)
        tg[(size_t)(n0 + s) * D + j] = tanhf(acc[s] * inv[s]);
}

// K3: per segment — score each token against tg[seg], accumulate weighted sum (rep),
// then broadcast rep to every token row of the segment. emb is read ONCE (score and
// accumulation share the same float4 registers).
__global__ void score_rep_kernel(const float* __restrict__ emb,
                                 const int* __restrict__ obj, int T,
                                 const float* __restrict__ tg,
                                 float* __restrict__ out) {
    const int seg   = blockIdx.x;
    const int start = lower_bound_dev(obj, T, seg);
    const int end   = lower_bound_dev(obj, T, seg + 1);
    if (start >= end) return;   // uniform across block; empty segment writes nothing

    const int tid  = threadIdx.x;
    const int lane = tid & 63;
    const int w    = tid >> 6;

    __shared__ float tgs[D];
    tgs[tid] = tg[(size_t)seg * D + tid];
    __syncthreads();
    const float4 tg4 = *reinterpret_cast<const float4*>(&tgs[lane * 4]);

    float4 acc = make_float4(0.f, 0.f, 0.f, 0.f);
    for (int r = start + w; r < end; r += 4) {
        const float4 e = *reinterpret_cast<const float4*>(emb + (size_t)r * D + lane * 4);
        float p = e.x * tg4.x + e.y * tg4.y + e.z * tg4.z + e.w * tg4.w;
        #pragma unroll
        for (int off = 32; off >= 1; off >>= 1) p += __shfl_xor(p, off, 64);
        const float score = 1.0f / (1.0f + __expf(-p));
        acc.x += e.x * score; acc.y += e.y * score;
        acc.z += e.z * score; acc.w += e.w * score;
    }

    __shared__ float rm[4][D];
    *reinterpret_cast<float4*>(&rm[w][lane * 4]) = acc;
    __syncthreads();
    // column-wise reduce: each thread owns column tid, no races
    rm[0][tid] = rm[0][tid] + rm[1][tid] + rm[2][tid] + rm[3][tid];
    __syncthreads();

    const float4 rep4 = *reinterpret_cast<const float4*>(&rm[0][lane * 4]);
    for (int r = start + w; r < end; r += 4) {
        *reinterpret_cast<float4*>(out + (size_t)r * D + lane * 4) = rep4;
    }
}

extern "C" void kernel_launch(void* const* d_in, const int* in_sizes, int n_in,
                              void* d_out, int out_size, void* d_ws, size_t ws_size,
                              hipStream_t stream) {
    const float* emb = (const float*)d_in[0];
    const float* W   = (const float*)d_in[1];
    const int*   obj = (const int*)d_in[2];
    const int T = in_sizes[2];

    float* out = (float*)d_out;

    // workspace layout: S [NSEG*D] f32 | tg [NSEG*D] f32 | counts [NSEG] i32  (~16.03 MB)
    float* S      = (float*)d_ws;
    float* tg     = S + (size_t)NSEG * D;
    int*   counts = (int*)(tg + (size_t)NSEG * D);

    seg_sum_kernel<<<NSEG, 256, 0, stream>>>(emb, obj, T, S, counts);
    proj_tanh_kernel<<<NSEG / SPB, 256, 0, stream>>>(S, counts, W, tg);
    score_rep_kernel<<<NSEG, 256, 0, stream>>>(emb, obj, T, tg, out);
}

// Round 2
// 991.049 us; speedup vs baseline: 1.0282x; 1.0282x over previous
//
#include <hip/hip_runtime.h>
#include <math.h>

#define D 256
#define NSEG 8192

__device__ __forceinline__ int lower_bound_dev(const int* __restrict__ a, int n, int key) {
    int lo = 0, hi = n;
    while (lo < hi) {
        int mid = (lo + hi) >> 1;
        if (a[mid] < key) lo = mid + 1; else hi = mid;
    }
    return lo;
}

// One block (256 threads = 4 waves) per segment. Fully fused:
//   pass 1: segment sum of emb rows (HBM read, coalesced float4)
//   proj  : tg = tanh((s @ W) / cnt)   -- W stays L2-resident across blocks
//   pass 2: re-read same rows (L2/LLC-hot), score = sigmoid(row . tg),
//           rep += row * score, then broadcast rep to every row of the segment.
__global__ __launch_bounds__(256) void fused_seg_kernel(
        const float* __restrict__ emb,
        const float* __restrict__ W,
        const int*   __restrict__ obj, int T,
        float* __restrict__ out) {
    const int seg   = blockIdx.x;
    const int start = lower_bound_dev(obj, T, seg);
    const int end   = lower_bound_dev(obj, T, seg + 1);
    if (start >= end) return;   // empty segment: no tokens reference it, nothing to write

    const int tid  = threadIdx.x;
    const int lane = tid & 63;
    const int w    = tid >> 6;

    __shared__ float sm[4][D];   // cross-wave reduction scratch
    __shared__ float sv[D];      // segment sum
    __shared__ float tg[D];      // transformed global context

    // ---- pass 1: segment sum ----
    float4 acc = make_float4(0.f, 0.f, 0.f, 0.f);
    for (int r = start + w; r < end; r += 4) {
        const float4 e = *reinterpret_cast<const float4*>(emb + (size_t)r * D + lane * 4);
        acc.x += e.x; acc.y += e.y; acc.z += e.z; acc.w += e.w;
    }
    *reinterpret_cast<float4*>(&sm[w][lane * 4]) = acc;
    __syncthreads();
    sv[tid] = sm[0][tid] + sm[1][tid] + sm[2][tid] + sm[3][tid];
    __syncthreads();

    // ---- projection: thread tid owns column j=tid of W ----
    // reads are coalesced per-k (256 consecutive floats); W (256 KB) is L2-hot.
    const float inv = 1.0f / (float)(end - start);
    float p = 0.f;
    #pragma unroll 8
    for (int k = 0; k < D; ++k) {
        p += sv[k] * W[k * D + tid];
    }
    tg[tid] = tanhf(p * inv);
    __syncthreads();
    const float4 tg4 = *reinterpret_cast<const float4*>(&tg[lane * 4]);

    // ---- pass 2: score + weighted sum (rows are L2/LLC-hot from pass 1) ----
    float4 racc = make_float4(0.f, 0.f, 0.f, 0.f);
    for (int r = start + w; r < end; r += 4) {
        const float4 e = *reinterpret_cast<const float4*>(emb + (size_t)r * D + lane * 4);
        float pd = e.x * tg4.x + e.y * tg4.y + e.z * tg4.z + e.w * tg4.w;
        #pragma unroll
        for (int off = 32; off >= 1; off >>= 1) pd += __shfl_xor(pd, off, 64);
        const float score = 1.0f / (1.0f + __expf(-pd));
        racc.x += e.x * score; racc.y += e.y * score;
        racc.z += e.z * score; racc.w += e.w * score;
    }
    *reinterpret_cast<float4*>(&sm[w][lane * 4]) = racc;
    __syncthreads();
    sm[0][tid] = sm[0][tid] + sm[1][tid] + sm[2][tid] + sm[3][tid];
    __syncthreads();
    const float4 rep4 = *reinterpret_cast<const float4*>(&sm[0][lane * 4]);

    // ---- broadcast rep to every token row of the segment ----
    for (int r = start + w; r < end; r += 4) {
        *reinterpret_cast<float4*>(out + (size_t)r * D + lane * 4) = rep4;
    }
}

extern "C" void kernel_launch(void* const* d_in, const int* in_sizes, int n_in,
                              void* d_out, int out_size, void* d_ws, size_t ws_size,
                              hipStream_t stream) {
    const float* emb = (const float*)d_in[0];
    const float* W   = (const float*)d_in[1];
    const int*   obj = (const int*)d_in[2];
    const int T = in_sizes[2];
    float* out = (float*)d_out;

    fused_seg_kernel<<<NSEG, 256, 0, stream>>>(emb, W, obj, T, out);
}